// Round 9
// baseline (202.825 us; speedup 1.0000x reference)
//
#include <hip/hip_runtime.h>

#define PIX 262144   // 512*512
#define CCH 64
#define KK  16

typedef __attribute__((ext_vector_type(8))) short short8;
typedef __attribute__((ext_vector_type(4))) float f32x4;

__device__ __forceinline__ float wred64(float v) {
    #pragma unroll
    for (int o = 32; o > 0; o >>= 1) v += __shfl_xor(v, o, 64);
    return v;
}

// ---------------- K2: one kernel does everything ------------------------------------
// blocks [0,2048):    A-pass: psum_c += M@X1^T, psumsq_c += M@(X1^2)^T, counts (128px)
// blocks [2048,4096): B-pass: G_c += M@(y*X2)^T, y computed IN-BLOCK from x2.
// MFMA 16x16x32 bf16: A[m=lane&15][k=quad*8+j] = mask m (0/1 exact);
// B[k][n'] = x split hi+lo (truncation, rel err <= 2^-16); D col=lane&15, row=quad*4+reg.
// Mask row needed by lane = n = lane&15 -> load raw masks[n][px], no packing pass.
// B-pass ynorm: block holds all 64 ch x 128 px; per-px sum via 4 xor-shuffles (over n)
// + LDS [pix][wave] float4 reduce -> rsqrt -> scale x before MFMA.
__global__ __launch_bounds__(256) void k2_all(
        const float* __restrict__ x1, const float* __restrict__ x2,
        const int* __restrict__ masks, float* __restrict__ counts_s,
        float* __restrict__ psum_c, float* __restrict__ psumsq_c,
        float* __restrict__ G_c) {
    __shared__ float ylds[128][4];
    int b = blockIdx.x;
    bool TB = (b >= 2048);
    if (TB) b -= 2048;
    int lane = threadIdx.x & 63;
    int wv   = threadIdx.x >> 6;
    int quad = lane >> 4;
    int n    = lane & 15;
    int ch   = wv * 16 + n;
    int base = b * 128;
    int cp   = b & 31;

    const float* Xrow = (TB ? x2 : x1) + (size_t)ch * PIX;
    const int*   Mrow = masks + (size_t)n * PIX;

    // stage all global loads upfront (24 x 16B per lane)
    int4 mk[8]; float4 xa[4], xb[4];
    #pragma unroll
    for (int i = 0; i < 4; ++i) {
        int kof = base + i * 32 + (quad << 3);
        mk[2*i]   = *(const int4*)(Mrow + kof);
        mk[2*i+1] = *(const int4*)(Mrow + kof + 4);
        xa[i] = *(const float4*)(Xrow + kof);
        xb[i] = *(const float4*)(Xrow + kof + 4);
    }

    float xs[4][8], sq[4][8];
    #pragma unroll
    for (int i = 0; i < 4; ++i) {
        xs[i][0]=xa[i].x; xs[i][1]=xa[i].y; xs[i][2]=xa[i].z; xs[i][3]=xa[i].w;
        xs[i][4]=xb[i].x; xs[i][5]=xb[i].y; xs[i][6]=xb[i].z; xs[i][7]=xb[i].w;
        #pragma unroll
        for (int j = 0; j < 8; ++j) sq[i][j] = xs[i][j] * xs[i][j];
    }

    if (TB) {
        // per-pixel ||x2col||^2: reduce sq over n (16 lanes in quad) then 4 waves
        #pragma unroll
        for (int off = 1; off < 16; off <<= 1)
            #pragma unroll
            for (int i = 0; i < 4; ++i)
                #pragma unroll
                for (int j = 0; j < 8; ++j)
                    sq[i][j] += __shfl_xor(sq[i][j], off, 64);
        if (n == 0) {
            #pragma unroll
            for (int i = 0; i < 4; ++i)
                #pragma unroll
                for (int j = 0; j < 8; ++j)
                    ylds[i * 32 + (quad << 3) + j][wv] = sq[i][j];
        }
        __syncthreads();
        #pragma unroll
        for (int i = 0; i < 4; ++i)
            #pragma unroll
            for (int j = 0; j < 8; ++j) {
                float4 v = *(const float4*)ylds[i * 32 + (quad << 3) + j];
                float s = v.x + v.y + v.z + v.w;
                float y = (s > 0.f) ? rsqrtf(s) : 0.f;
                xs[i][j] *= y;
            }
    } else if (wv == 0) {
        // counts[k=n] over this block's 128 px
        int cnt = 0;
        #pragma unroll
        for (int i = 0; i < 8; ++i) {
            cnt += (mk[i].x == 1) + (mk[i].y == 1) + (mk[i].z == 1) + (mk[i].w == 1);
        }
        float fc = (float)cnt;
        fc += __shfl_xor(fc, 16, 64);
        fc += __shfl_xor(fc, 32, 64);
        if (quad == 0) atomicAdd(counts_s + n * 32 + cp, fc);
    }

    f32x4 acc0 = {0.f, 0.f, 0.f, 0.f};
    f32x4 acc1 = {0.f, 0.f, 0.f, 0.f};
    const short ONE = (short)0x3F80;   // bf16 1.0

    #pragma unroll
    for (int i = 0; i < 4; ++i) {
        short8 af;
        af[0] = (mk[2*i].x   == 1) ? ONE : (short)0;
        af[1] = (mk[2*i].y   == 1) ? ONE : (short)0;
        af[2] = (mk[2*i].z   == 1) ? ONE : (short)0;
        af[3] = (mk[2*i].w   == 1) ? ONE : (short)0;
        af[4] = (mk[2*i+1].x == 1) ? ONE : (short)0;
        af[5] = (mk[2*i+1].y == 1) ? ONE : (short)0;
        af[6] = (mk[2*i+1].z == 1) ? ONE : (short)0;
        af[7] = (mk[2*i+1].w == 1) ? ONE : (short)0;

        short8 bh, bl;
        #pragma unroll
        for (int j = 0; j < 8; ++j) {
            float v = xs[i][j];
            unsigned u = __float_as_uint(v);
            bh[j] = (short)(u >> 16);
            float hi = __uint_as_float(u & 0xFFFF0000u);
            bl[j] = (short)(__float_as_uint(v - hi) >> 16);
        }
        acc0 = __builtin_amdgcn_mfma_f32_16x16x32_bf16(af, bh, acc0, 0, 0, 0);
        acc0 = __builtin_amdgcn_mfma_f32_16x16x32_bf16(af, bl, acc0, 0, 0, 0);

        if (!TB) {
            short8 qh, ql;
            #pragma unroll
            for (int j = 0; j < 8; ++j) {
                float v = sq[i][j];
                unsigned u = __float_as_uint(v);
                qh[j] = (short)(u >> 16);
                float hi = __uint_as_float(u & 0xFFFF0000u);
                ql[j] = (short)(__float_as_uint(v - hi) >> 16);
            }
            acc1 = __builtin_amdgcn_mfma_f32_16x16x32_bf16(af, qh, acc1, 0, 0, 0);
            acc1 = __builtin_amdgcn_mfma_f32_16x16x32_bf16(af, ql, acc1, 0, 0, 0);
        }
    }

    int col = wv * 16 + n;
    #pragma unroll
    for (int r = 0; r < 4; ++r) {
        int idx = cp * 1024 + (quad * 4 + r) * 64 + col;
        if (TB) {
            atomicAdd(G_c + idx, acc0[r]);
        } else {
            atomicAdd(psum_c + idx, acc0[r]);
            atomicAdd(psumsq_c + idx, acc1[r]);
        }
    }
}

// ---------------- K3: reduce 32 copies + finalize (fully parallel, LDS only) -------
__global__ __launch_bounds__(256) void k3_finalize(
        const int* __restrict__ labels, const float* __restrict__ counts_s,
        const float* __restrict__ psum_c, const float* __restrict__ psumsq_c,
        const float* __restrict__ G_c, float* __restrict__ out) {
    __shared__ float meansS[16][65];
    __shared__ float Gs[16][65];
    __shared__ float cntS[16], rawcS[16], nmS[16], stdS[16], rowS[16];
    __shared__ float ssq2[16][17];
    __shared__ float ssqS[16];
    __shared__ int   labS[16];
    __shared__ float simS[16][17];
    __shared__ float bred[4][6];
    int t = threadIdx.x;

    if (t < 16) {
        float s = 0.f;
        #pragma unroll 8
        for (int j = 0; j < 32; ++j) s += counts_s[t * 32 + j];
        rawcS[t] = s;
        cntS[t]  = fmaxf(s, 1.f);
        labS[t]  = labels[t];
    }
    {
        int k = t >> 4, seg = t & 15;
        float s = 0.f;
        for (int cp = 0; cp < 32; ++cp) {
            const float4 v = *(const float4*)(psumsq_c + cp * 1024 + k * 64 + seg * 4);
            s += v.x + v.y + v.z + v.w;
        }
        ssq2[k][seg] = s;
    }
    __syncthreads();
    if (t < 16) {
        float s = 0.f;
        #pragma unroll
        for (int seg = 0; seg < 16; ++seg) s += ssq2[t][seg];
        ssqS[t] = s;
    }
    for (int i = t; i < 1024; i += 256) {
        int k = i >> 6, c = i & 63;
        float sp = 0.f, sg = 0.f;
        #pragma unroll 8
        for (int cp = 0; cp < 32; ++cp) {
            sp += psum_c[cp * 1024 + i];
            sg += G_c[cp * 1024 + i];
        }
        meansS[k][c] = sp / cntS[k];
        Gs[k][c] = sg;
    }
    __syncthreads();
    if (t < 16) {
        float s2 = 0.f, sm = 0.f;
        for (int c = 0; c < 64; ++c) {
            float m = meansS[t][c];
            s2 = fmaf(m, m, s2);
            sm += m;
        }
        nmS[t] = sqrtf(s2);
        float ne = rawcS[t] * 64.f;
        float ma = (sm * cntS[t]) / fmaxf(ne, 1.f);
        float var = (ssqS[t] - ne * ma * ma) / fmaxf(ne - 1.f, 1.f);
        stdS[t] = sqrtf(fmaxf(var, 0.f));
    }
    __syncthreads();
    {
        int i = t >> 4, j = t & 15;
        float d = 0.f;
        #pragma unroll 16
        for (int c = 0; c < 64; ++c) d = fmaf(meansS[i][c], Gs[j][c], d);
        simS[i][j] = d / (fmaxf(nmS[i], 1e-30f) * cntS[j]);
    }
    __syncthreads();
    if (t < 16) {
        float s = 0.f;
        int li = labS[t];
        for (int j = 0; j < 16; ++j)
            if (j != t && labS[j] == li) s += simS[t][j];
        rowS[t] = s;
    }
    float s0 = 0.f, s1 = 0.f, s2 = 0.f, c0 = 0.f, c1 = 0.f, c2 = 0.f;
    {
        int i = t >> 4, j = t & 15;
        int li = labS[i], lj = labS[j];
        if (li != lj) {
            float sv = simS[i][j];
            bool gi0 = li >= 1 && li <= 8,  gj0 = lj >= 1 && lj <= 8;
            bool gi1 = li >= 3 && li <= 10, gj1 = lj >= 3 && lj <= 10;
            bool gi2 = (li >= 1 && li <= 2) || (li >= 9 && li <= 10);
            bool gj2 = (lj >= 1 && lj <= 2) || (lj >= 9 && lj <= 10);
            if (gi0 && gj0) { s0 = sv; c0 = 1.f; }
            if (gi1 && gj1) { s1 = sv; c1 = 1.f; }
            if (gi2 && gj2) { s2 = sv; c2 = 1.f; }
        }
    }
    s0 = wred64(s0); s1 = wred64(s1); s2 = wred64(s2);
    c0 = wred64(c0); c1 = wred64(c1); c2 = wred64(c2);
    {
        int wid = t >> 6, lane = t & 63;
        if (lane == 0) {
            bred[wid][0] = s0; bred[wid][1] = s1; bred[wid][2] = s2;
            bred[wid][3] = c0; bred[wid][4] = c1; bred[wid][5] = c2;
        }
    }
    __syncthreads();
    if (t < 11) {
        float cc = 0.f, inst = 0.f, csim = 0.f, cstd = 0.f;
        for (int k = 0; k < 16; ++k) {
            if (labS[k] == t) {
                cc += 1.f;
                inst += simS[k][k];
                csim += rowS[k];
                cstd += stdS[k];
            }
        }
        if (cc > 1.f) {
            inst /= fmaxf(cc, 1.f);
            csim /= fmaxf(cc * (cc - 1.f), 1.f);
            cstd /= cc;
        }
        out[t]      = inst;
        out[11 + t] = csim;
        out[25 + t] = cstd;
    }
    if (t == 0) {
        float S0 = bred[0][0] + bred[1][0] + bred[2][0] + bred[3][0];
        float S1 = bred[0][1] + bred[1][1] + bred[2][1] + bred[3][1];
        float S2 = bred[0][2] + bred[1][2] + bred[2][2] + bred[3][2];
        float C0 = bred[0][3] + bred[1][3] + bred[2][3] + bred[3][3];
        float C1 = bred[0][4] + bred[1][4] + bred[2][4] + bred[3][4];
        float C2 = bred[0][5] + bred[1][5] + bred[2][5] + bred[3][5];
        out[22] = (C0 > 1.f) ? (S0 / C0) : S0;
        out[23] = (C1 > 1.f) ? (S1 / C1) : S1;
        out[24] = (C2 > 1.f) ? (S2 / C2) : S2;
    }
}

extern "C" void kernel_launch(void* const* d_in, const int* in_sizes, int n_in,
                              void* d_out, int out_size, void* d_ws, size_t ws_size,
                              hipStream_t stream) {
    const float* x1     = (const float*)d_in[0];
    const float* x2     = (const float*)d_in[1];
    const int*   masks  = (const int*)d_in[2];
    const int*   labels = (const int*)d_in[3];
    float* out = (float*)d_out;

    float* ws = (float*)d_ws;
    float* counts_s = ws;                    // 512 f
    float* psum_c   = counts_s + 512;        // 32*1024 f
    float* psumsq_c = psum_c + 32 * 1024;    // 32*1024 f
    float* G_c      = psumsq_c + 32 * 1024;  // 32*1024 f

    hipMemsetAsync(counts_s, 0, (512 + 3 * 32 * 1024) * sizeof(float), stream);
    k2_all<<<4096, 256, 0, stream>>>(x1, x2, masks, counts_s, psum_c, psumsq_c, G_c);
    k3_finalize<<<1, 256, 0, stream>>>(labels, counts_s, psum_c, psumsq_c, G_c, out);
}

// Round 10
// 188.586 us; speedup vs baseline: 1.0755x; 1.0755x over previous
//
#include <hip/hip_runtime.h>

#define PIX 262144   // 512*512
#define CCH 64
#define KK  16

typedef __attribute__((ext_vector_type(8))) short short8;
typedef __attribute__((ext_vector_type(4))) float f32x4;

__device__ __forceinline__ float wred64(float v) {
    #pragma unroll
    for (int o = 32; o > 0; o >>= 1) v += __shfl_xor(v, o, 64);
    return v;
}

// ---------------- K2: single fused accumulation kernel -----------------------------
// 1024 blocks x 512 px each.
// blocks [0,512):    A-pass: psum_c += M@X1^T, psumsq_c += M@(X1^2)^T, counts.
//   Wave wv owns channels wv*16+n; loop 4 x 128-px super-chunks; atomics once at end.
// blocks [512,1024): B-pass: G_c += M@(y*X2)^T with y computed per-wave (NO barrier):
//   wave wv owns px stripe [it*128+wv*32), lane (quad,n) loads 4 channel-groups
//   (ch = cg*16+n) for its 8 px; ||x2||^2 = local cg-sum + 4 xor-shuffles over n;
//   4 accumulators (one per cg); end-of-block LDS reduce -> 1024 atomics.
// MFMA 16x16x32 bf16: A[m=lane&15][k=quad*8+j] = mask (0/1 exact); B split hi/lo
// (truncation, rel err <= 2^-16); D col=lane&15, row=quad*4+reg (HW-verified R6-R9).
__global__ __launch_bounds__(256) void k2_all(
        const float* __restrict__ x1, const float* __restrict__ x2,
        const int* __restrict__ masks, float* __restrict__ counts_s,
        float* __restrict__ psum_c, float* __restrict__ psumsq_c,
        float* __restrict__ G_c) {
    __shared__ float gl[4][1024];
    int lane = threadIdx.x & 63;
    int wv   = threadIdx.x >> 6;
    int quad = lane >> 4;
    int n    = lane & 15;
    const short ONE = (short)0x3F80;   // bf16 1.0
    const int* Mrow = masks + (size_t)n * PIX;

    if (blockIdx.x < 512) {
        // ---------------- A-pass ----------------
        int b = blockIdx.x;
        int base = b * 512;
        int cp   = b & 31;
        const float* Xrow = x1 + (size_t)(wv * 16 + n) * PIX;

        f32x4 acc0 = {0.f, 0.f, 0.f, 0.f};
        f32x4 acc1 = {0.f, 0.f, 0.f, 0.f};
        int cnt = 0;

        for (int sc = 0; sc < 4; ++sc) {
            int4 mk[8]; float4 xa[4], xb[4];
            #pragma unroll
            for (int i = 0; i < 4; ++i) {
                int kof = base + sc * 128 + i * 32 + (quad << 3);
                mk[2*i]   = *(const int4*)(Mrow + kof);
                mk[2*i+1] = *(const int4*)(Mrow + kof + 4);
                xa[i] = *(const float4*)(Xrow + kof);
                xb[i] = *(const float4*)(Xrow + kof + 4);
            }
            #pragma unroll
            for (int i = 0; i < 4; ++i) {
                short8 af;
                af[0] = (mk[2*i].x   == 1) ? ONE : (short)0;
                af[1] = (mk[2*i].y   == 1) ? ONE : (short)0;
                af[2] = (mk[2*i].z   == 1) ? ONE : (short)0;
                af[3] = (mk[2*i].w   == 1) ? ONE : (short)0;
                af[4] = (mk[2*i+1].x == 1) ? ONE : (short)0;
                af[5] = (mk[2*i+1].y == 1) ? ONE : (short)0;
                af[6] = (mk[2*i+1].z == 1) ? ONE : (short)0;
                af[7] = (mk[2*i+1].w == 1) ? ONE : (short)0;
                cnt += (mk[2*i].x == 1) + (mk[2*i].y == 1) + (mk[2*i].z == 1) + (mk[2*i].w == 1)
                     + (mk[2*i+1].x == 1) + (mk[2*i+1].y == 1) + (mk[2*i+1].z == 1) + (mk[2*i+1].w == 1);

                float xs[8] = {xa[i].x, xa[i].y, xa[i].z, xa[i].w,
                               xb[i].x, xb[i].y, xb[i].z, xb[i].w};
                short8 bh, bl, qh, ql;
                #pragma unroll
                for (int j = 0; j < 8; ++j) {
                    float v = xs[j];
                    unsigned u = __float_as_uint(v);
                    bh[j] = (short)(u >> 16);
                    float hi = __uint_as_float(u & 0xFFFF0000u);
                    bl[j] = (short)(__float_as_uint(v - hi) >> 16);
                    float sqv = v * v;
                    unsigned uq = __float_as_uint(sqv);
                    qh[j] = (short)(uq >> 16);
                    float hq = __uint_as_float(uq & 0xFFFF0000u);
                    ql[j] = (short)(__float_as_uint(sqv - hq) >> 16);
                }
                acc0 = __builtin_amdgcn_mfma_f32_16x16x32_bf16(af, bh, acc0, 0, 0, 0);
                acc0 = __builtin_amdgcn_mfma_f32_16x16x32_bf16(af, bl, acc0, 0, 0, 0);
                acc1 = __builtin_amdgcn_mfma_f32_16x16x32_bf16(af, qh, acc1, 0, 0, 0);
                acc1 = __builtin_amdgcn_mfma_f32_16x16x32_bf16(af, ql, acc1, 0, 0, 0);
            }
        }

        int col = wv * 16 + n;
        #pragma unroll
        for (int r = 0; r < 4; ++r) {
            int idx = cp * 1024 + (quad * 4 + r) * 64 + col;
            atomicAdd(psum_c + idx, acc0[r]);
            atomicAdd(psumsq_c + idx, acc1[r]);
        }
        if (wv == 0) {
            float fc = (float)cnt;
            fc += __shfl_xor(fc, 16, 64);
            fc += __shfl_xor(fc, 32, 64);
            if (quad == 0) atomicAdd(counts_s + n * 32 + cp, fc);
        }
    } else {
        // ---------------- B-pass (barrier-free ynorm) ----------------
        int b = blockIdx.x - 512;
        int base = b * 512;
        int cp   = b & 31;

        f32x4 acc[4];
        #pragma unroll
        for (int cg = 0; cg < 4; ++cg) acc[cg] = (f32x4){0.f, 0.f, 0.f, 0.f};

        for (int it = 0; it < 4; ++it) {
            int pxo = base + it * 128 + wv * 32 + (quad << 3);
            int4 mk0 = *(const int4*)(Mrow + pxo);
            int4 mk1 = *(const int4*)(Mrow + pxo + 4);
            float4 xla[4], xlb[4];
            #pragma unroll
            for (int cg = 0; cg < 4; ++cg) {
                const float* Xr = x2 + (size_t)(cg * 16 + n) * PIX;
                xla[cg] = *(const float4*)(Xr + pxo);
                xlb[cg] = *(const float4*)(Xr + pxo + 4);
            }

            float xs[4][8];
            #pragma unroll
            for (int cg = 0; cg < 4; ++cg) {
                xs[cg][0]=xla[cg].x; xs[cg][1]=xla[cg].y; xs[cg][2]=xla[cg].z; xs[cg][3]=xla[cg].w;
                xs[cg][4]=xlb[cg].x; xs[cg][5]=xlb[cg].y; xs[cg][6]=xlb[cg].z; xs[cg][7]=xlb[cg].w;
            }
            float ss[8];
            #pragma unroll
            for (int j = 0; j < 8; ++j) {
                float s = xs[0][j] * xs[0][j];
                s = fmaf(xs[1][j], xs[1][j], s);
                s = fmaf(xs[2][j], xs[2][j], s);
                s = fmaf(xs[3][j], xs[3][j], s);
                ss[j] = s;
            }
            #pragma unroll
            for (int off = 1; off < 16; off <<= 1)
                #pragma unroll
                for (int j = 0; j < 8; ++j)
                    ss[j] += __shfl_xor(ss[j], off, 64);
            float yw[8];
            #pragma unroll
            for (int j = 0; j < 8; ++j)
                yw[j] = (ss[j] > 0.f) ? rsqrtf(ss[j]) : 0.f;

            short8 af;
            af[0] = (mk0.x == 1) ? ONE : (short)0;
            af[1] = (mk0.y == 1) ? ONE : (short)0;
            af[2] = (mk0.z == 1) ? ONE : (short)0;
            af[3] = (mk0.w == 1) ? ONE : (short)0;
            af[4] = (mk1.x == 1) ? ONE : (short)0;
            af[5] = (mk1.y == 1) ? ONE : (short)0;
            af[6] = (mk1.z == 1) ? ONE : (short)0;
            af[7] = (mk1.w == 1) ? ONE : (short)0;

            #pragma unroll
            for (int cg = 0; cg < 4; ++cg) {
                short8 bh, bl;
                #pragma unroll
                for (int j = 0; j < 8; ++j) {
                    float v = xs[cg][j] * yw[j];
                    unsigned u = __float_as_uint(v);
                    bh[j] = (short)(u >> 16);
                    float hi = __uint_as_float(u & 0xFFFF0000u);
                    bl[j] = (short)(__float_as_uint(v - hi) >> 16);
                }
                acc[cg] = __builtin_amdgcn_mfma_f32_16x16x32_bf16(af, bh, acc[cg], 0, 0, 0);
                acc[cg] = __builtin_amdgcn_mfma_f32_16x16x32_bf16(af, bl, acc[cg], 0, 0, 0);
            }
        }

        // cross-wave reduce (disjoint px -> partial sums of same [16][64] tile)
        #pragma unroll
        for (int cg = 0; cg < 4; ++cg)
            #pragma unroll
            for (int r = 0; r < 4; ++r)
                gl[wv][(quad * 4 + r) * 64 + cg * 16 + n] = acc[cg][r];
        __syncthreads();
        for (int e = threadIdx.x; e < 1024; e += 256) {
            float s = gl[0][e] + gl[1][e] + gl[2][e] + gl[3][e];
            atomicAdd(G_c + cp * 1024 + e, s);
        }
    }
}

// ---------------- K3: reduce 32 copies + finalize (fully parallel, LDS only) -------
__global__ __launch_bounds__(256) void k3_finalize(
        const int* __restrict__ labels, const float* __restrict__ counts_s,
        const float* __restrict__ psum_c, const float* __restrict__ psumsq_c,
        const float* __restrict__ G_c, float* __restrict__ out) {
    __shared__ float meansS[16][65];
    __shared__ float Gs[16][65];
    __shared__ float cntS[16], rawcS[16], nmS[16], stdS[16], rowS[16];
    __shared__ float ssq2[16][17];
    __shared__ float ssqS[16];
    __shared__ int   labS[16];
    __shared__ float simS[16][17];
    __shared__ float bred[4][6];
    int t = threadIdx.x;

    if (t < 16) {
        float s = 0.f;
        #pragma unroll 8
        for (int j = 0; j < 32; ++j) s += counts_s[t * 32 + j];
        rawcS[t] = s;
        cntS[t]  = fmaxf(s, 1.f);
        labS[t]  = labels[t];
    }
    {
        int k = t >> 4, seg = t & 15;
        float s = 0.f;
        for (int cp = 0; cp < 32; ++cp) {
            const float4 v = *(const float4*)(psumsq_c + cp * 1024 + k * 64 + seg * 4);
            s += v.x + v.y + v.z + v.w;
        }
        ssq2[k][seg] = s;
    }
    __syncthreads();
    if (t < 16) {
        float s = 0.f;
        #pragma unroll
        for (int seg = 0; seg < 16; ++seg) s += ssq2[t][seg];
        ssqS[t] = s;
    }
    for (int i = t; i < 1024; i += 256) {
        int k = i >> 6, c = i & 63;
        float sp = 0.f, sg = 0.f;
        #pragma unroll 8
        for (int cp = 0; cp < 32; ++cp) {
            sp += psum_c[cp * 1024 + i];
            sg += G_c[cp * 1024 + i];
        }
        meansS[k][c] = sp / cntS[k];
        Gs[k][c] = sg;
    }
    __syncthreads();
    if (t < 16) {
        float s2 = 0.f, sm = 0.f;
        for (int c = 0; c < 64; ++c) {
            float m = meansS[t][c];
            s2 = fmaf(m, m, s2);
            sm += m;
        }
        nmS[t] = sqrtf(s2);
        float ne = rawcS[t] * 64.f;
        float ma = (sm * cntS[t]) / fmaxf(ne, 1.f);
        float var = (ssqS[t] - ne * ma * ma) / fmaxf(ne - 1.f, 1.f);
        stdS[t] = sqrtf(fmaxf(var, 0.f));
    }
    __syncthreads();
    {
        int i = t >> 4, j = t & 15;
        float d = 0.f;
        #pragma unroll 16
        for (int c = 0; c < 64; ++c) d = fmaf(meansS[i][c], Gs[j][c], d);
        simS[i][j] = d / (fmaxf(nmS[i], 1e-30f) * cntS[j]);
    }
    __syncthreads();
    if (t < 16) {
        float s = 0.f;
        int li = labS[t];
        for (int j = 0; j < 16; ++j)
            if (j != t && labS[j] == li) s += simS[t][j];
        rowS[t] = s;
    }
    float s0 = 0.f, s1 = 0.f, s2 = 0.f, c0 = 0.f, c1 = 0.f, c2 = 0.f;
    {
        int i = t >> 4, j = t & 15;
        int li = labS[i], lj = labS[j];
        if (li != lj) {
            float sv = simS[i][j];
            bool gi0 = li >= 1 && li <= 8,  gj0 = lj >= 1 && lj <= 8;
            bool gi1 = li >= 3 && li <= 10, gj1 = lj >= 3 && lj <= 10;
            bool gi2 = (li >= 1 && li <= 2) || (li >= 9 && li <= 10);
            bool gj2 = (lj >= 1 && lj <= 2) || (lj >= 9 && lj <= 10);
            if (gi0 && gj0) { s0 = sv; c0 = 1.f; }
            if (gi1 && gj1) { s1 = sv; c1 = 1.f; }
            if (gi2 && gj2) { s2 = sv; c2 = 1.f; }
        }
    }
    s0 = wred64(s0); s1 = wred64(s1); s2 = wred64(s2);
    c0 = wred64(c0); c1 = wred64(c1); c2 = wred64(c2);
    {
        int wid = t >> 6, lane = t & 63;
        if (lane == 0) {
            bred[wid][0] = s0; bred[wid][1] = s1; bred[wid][2] = s2;
            bred[wid][3] = c0; bred[wid][4] = c1; bred[wid][5] = c2;
        }
    }
    __syncthreads();
    if (t < 11) {
        float cc = 0.f, inst = 0.f, csim = 0.f, cstd = 0.f;
        for (int k = 0; k < 16; ++k) {
            if (labS[k] == t) {
                cc += 1.f;
                inst += simS[k][k];
                csim += rowS[k];
                cstd += stdS[k];
            }
        }
        if (cc > 1.f) {
            inst /= fmaxf(cc, 1.f);
            csim /= fmaxf(cc * (cc - 1.f), 1.f);
            cstd /= cc;
        }
        out[t]      = inst;
        out[11 + t] = csim;
        out[25 + t] = cstd;
    }
    if (t == 0) {
        float S0 = bred[0][0] + bred[1][0] + bred[2][0] + bred[3][0];
        float S1 = bred[0][1] + bred[1][1] + bred[2][1] + bred[3][1];
        float S2 = bred[0][2] + bred[1][2] + bred[2][2] + bred[3][2];
        float C0 = bred[0][3] + bred[1][3] + bred[2][3] + bred[3][3];
        float C1 = bred[0][4] + bred[1][4] + bred[2][4] + bred[3][4];
        float C2 = bred[0][5] + bred[1][5] + bred[2][5] + bred[3][5];
        out[22] = (C0 > 1.f) ? (S0 / C0) : S0;
        out[23] = (C1 > 1.f) ? (S1 / C1) : S1;
        out[24] = (C2 > 1.f) ? (S2 / C2) : S2;
    }
}

extern "C" void kernel_launch(void* const* d_in, const int* in_sizes, int n_in,
                              void* d_out, int out_size, void* d_ws, size_t ws_size,
                              hipStream_t stream) {
    const float* x1     = (const float*)d_in[0];
    const float* x2     = (const float*)d_in[1];
    const int*   masks  = (const int*)d_in[2];
    const int*   labels = (const int*)d_in[3];
    float* out = (float*)d_out;

    float* ws = (float*)d_ws;
    float* counts_s = ws;                    // 512 f
    float* psum_c   = counts_s + 512;        // 32*1024 f
    float* psumsq_c = psum_c + 32 * 1024;    // 32*1024 f
    float* G_c      = psumsq_c + 32 * 1024;  // 32*1024 f

    hipMemsetAsync(counts_s, 0, (512 + 3 * 32 * 1024) * sizeof(float), stream);
    k2_all<<<1024, 256, 0, stream>>>(x1, x2, masks, counts_s, psum_c, psumsq_c, G_c);
    k3_finalize<<<1, 256, 0, stream>>>(labels, counts_s, psum_c, psumsq_c, G_c, out);
}